// Round 2
// baseline (173.752 us; speedup 1.0000x reference)
//
#include <hip/hip_runtime.h>
#include <math.h>

// One wave (64 lanes) simulates one sample's 10-qubit state vector.
// Amplitude index i in [0,1024): bit q of i <-> qubit q.
//   bits 0..5  -> lane index   (cross-lane gates via shfl)
//   bits 6..9  -> register idx (in-register gates)
// Layer structure (x3): fused U_q = RX(theta_q) * RY(enc_q) on each qubit
// (valid: the intervening gates act on other qubits and commute), then the
// CNOT chain 0->1->...->9 collapsed to the single index permutation
//   src(i) = i ^ ((i & 511) << 1).
// All inputs/outputs are float32 per the reference (round-1 evidence:
// bf16 misread gave clamp-saturated garbage; 30.3232 > 30 + max|ref|
// proved the out buffer is read as fp32).

#define PI_F 3.14159265358979323846f

__global__ __launch_bounds__(256, 1) void cqv_kernel(
    const float* __restrict__ x,
    const float* __restrict__ theta,
    const float* __restrict__ alpha_raw,
    const float* __restrict__ beta_raw,
    const float* __restrict__ head_w,
    const float* __restrict__ head_b,
    const float* __restrict__ logit_scale,
    float* __restrict__ out,
    int batch)
{
    const int lane = threadIdx.x & 63;
    const int wave = threadIdx.x >> 6;
    const int s = blockIdx.x * (blockDim.x >> 6) + wave;
    if (s >= batch) return;

    // ---- per-lane gate parameters: lane g in [0,30) holds gate g = b*10+q ----
    const int g = (lane < 30) ? lane : 0;
    const float araw  = alpha_raw[g];
    const float alpha = log1pf(expf(araw)) + 1e-6f;          // softplus + 1e-6
    const float beta  = tanhf(beta_raw[g]);                  // * ENC_BETA_MAX(=1)
    const float xg    = x[s * 49 + g];                       // fi = b*10+q (< 49)
    const float halfE = 0.5f * PI_F * (alpha * xg + beta);
    const float cE = cosf(halfE), sE = sinf(halfE);
    const float th = 0.5f * theta[g];
    const float cT = cosf(th), sT = sinf(th);

    // ---- state |0...0> ----
    float sr[16], si[16];
    #pragma unroll
    for (int r = 0; r < 16; ++r) { sr[r] = 0.f; si[r] = 0.f; }
    sr[0] = (lane == 0) ? 1.f : 0.f;

    #pragma unroll
    for (int b = 0; b < 3; ++b) {
        // ---- fused U = RX(theta) * RY(enc) on each qubit ----
        // U = [[A, B], [-conj(B), conj(A)]],  A = (ct*ce, -st*se), B = (-ct*se, -st*ce)
        #pragma unroll
        for (int q = 0; q < 10; ++q) {
            const int gi = b * 10 + q;
            const float ce = __shfl(cE, gi);
            const float se = __shfl(sE, gi);
            const float ct = __shfl(cT, gi);
            const float st = __shfl(sT, gi);
            const float ar = ct * ce,  ai = -st * se;
            const float br = -ct * se, bi = -st * ce;
            if (q < 6) {
                const int mask = 1 << q;
                const bool hi = (lane & mask) != 0;
                // bit=0: n = A*s + B*p ; bit=1: n = conj(A)*s - conj(B)*p
                const float aiL = hi ? -ai : ai;
                const float brL = hi ? -br : br;
                #pragma unroll
                for (int r = 0; r < 16; ++r) {
                    const float pr = __shfl_xor(sr[r], mask);
                    const float pi = __shfl_xor(si[r], mask);
                    const float vr = sr[r], vi = si[r];
                    sr[r] = ar * vr - aiL * vi + brL * pr - bi * pi;
                    si[r] = ar * vi + aiL * vr + brL * pi + bi * pr;
                }
            } else {
                const int rb = 1 << (q - 6);
                #pragma unroll
                for (int r = 0; r < 16; ++r) {
                    if ((r & rb) == 0) {
                        const int r1 = r | rb;
                        const float s0r = sr[r],  s0i = si[r];
                        const float s1r = sr[r1], s1i = si[r1];
                        sr[r]  = ar * s0r - ai * s0i + br * s1r - bi * s1i;
                        si[r]  = ar * s0i + ai * s0r + br * s1i + bi * s1r;
                        sr[r1] = ar * s1r + ai * s1i - br * s0r - bi * s0i;
                        si[r1] = ar * s1i - ai * s1r - br * s0i + bi * s0r;
                    }
                }
            }
        }
        // ---- CNOT chain as one permutation: src(i) = i ^ ((i&511)<<1) ----
        {
            const int srcLane = lane ^ ((lane & 31) << 1);
            float tr[16], ti[16];
            #pragma unroll
            for (int r = 0; r < 16; ++r) {
                tr[r] = __shfl(sr[r], srcLane);
                ti[r] = __shfl(si[r], srcLane);
            }
            const bool b5 = (lane & 32) != 0;  // lane bit 5 feeds reg bit 0
            #pragma unroll
            for (int r = 0; r < 16; ++r) {
                const int q0 = r ^ ((r & 7) << 1);
                const int q1 = q0 ^ 1;
                sr[r] = b5 ? tr[q1] : tr[q0];
                si[r] = b5 ? ti[q1] : ti[q0];
            }
        }
    }

    // ---- epilogue: out = clip(scale * (sum_i p_i * W(i) + head_b)) ----
    // W(i) = sum_q w_q * (1 - 2*bit_q(i)); split into lane part + reg part.
    float w[10];
    #pragma unroll
    for (int q = 0; q < 10; ++q) w[q] = head_w[q];
    float wlane = 0.f;
    #pragma unroll
    for (int q = 0; q < 6; ++q) wlane += ((lane >> q) & 1) ? -w[q] : w[q];
    float acc = 0.f, psum = 0.f;
    #pragma unroll
    for (int r = 0; r < 16; ++r) {
        const float p = sr[r] * sr[r] + si[r] * si[r];
        const float wr = ((r & 1) ? -w[6] : w[6]) + ((r & 2) ? -w[7] : w[7])
                       + ((r & 4) ? -w[8] : w[8]) + ((r & 8) ? -w[9] : w[9]);
        psum += p;
        acc = fmaf(wr, p, acc);
    }
    float partial = fmaf(wlane, psum, acc);
    #pragma unroll
    for (int off = 32; off >= 1; off >>= 1) partial += __shfl_xor(partial, off);

    if (lane == 0) {
        const float scale = fminf(fmaxf(logit_scale[0], 0.5f), 80.f);
        const float raw = partial + head_b[0];
        out[s] = fminf(fmaxf(scale * raw, -30.f), 30.f);
    }
}

extern "C" void kernel_launch(void* const* d_in, const int* in_sizes, int n_in,
                              void* d_out, int out_size, void* d_ws, size_t ws_size,
                              hipStream_t stream) {
    const int B = in_sizes[0] / 49;          // BATCH = 2048
    const int WPB = 4;                       // waves per block
    dim3 block(64 * WPB);
    dim3 grid((B + WPB - 1) / WPB);
    cqv_kernel<<<grid, block, 0, stream>>>(
        (const float*)d_in[0],   // x (B,49)
        (const float*)d_in[1],   // theta (30,)
        (const float*)d_in[2],   // enc_alpha_raw (49,)
        (const float*)d_in[3],   // enc_beta_raw (49,)
        (const float*)d_in[4],   // head_w (1,10)
        (const float*)d_in[5],   // head_b (1,)
        (const float*)d_in[6],   // logit_scale ()
        (float*)d_out, B);
}

// Round 3
// 90.209 us; speedup vs baseline: 1.9261x; 1.9261x over previous
//
#include <hip/hip_runtime.h>
#include <math.h>

// One wave = one sample's 10-qubit state. Amplitude i in [0,1024):
//   bits 0..5 -> lane, bits 6..9 -> register index (16 complex/lane).
// Layer = fused U_q = RX(theta)*RY(enc) per qubit, then CNOT chain collapsed
// to the permutation src(j) = j ^ ((j&511)<<1)  (inverse prefix-XOR).
// Layer 1 acts on |0..0> -> built directly as a product state (no gates).
// Lane-qubit gates use DPP for xor masks 1,2,8 (VALU pipe, no lgkm latency);
// masks 4,16,32 use __shfl_xor (ds_swizzle/bpermute).
// Layer loop is NOT unrolled: round-2's fully-unrolled ~90KB body streamed
// through the 32KB I$ with only 2 waves/SIMD -> 95% stall (VALUBusy 22%).

#define PI_F 3.14159265358979323846f

__device__ __forceinline__ float dpp_xor1(float v) {
    return __int_as_float(__builtin_amdgcn_update_dpp(
        0, __float_as_int(v), 0xB1, 0xF, 0xF, true));   // quad_perm [1,0,3,2]
}
__device__ __forceinline__ float dpp_xor2(float v) {
    return __int_as_float(__builtin_amdgcn_update_dpp(
        0, __float_as_int(v), 0x4E, 0xF, 0xF, true));   // quad_perm [2,3,0,1]
}
__device__ __forceinline__ float dpp_xor8(float v) {
    return __int_as_float(__builtin_amdgcn_update_dpp(
        0, __float_as_int(v), 0x128, 0xF, 0xF, true));  // row_ror:8 == lane^8 in 16-row
}

template<int Q>
__device__ __forceinline__ float lane_xor(float v) {
    if constexpr (Q == 0) return dpp_xor1(v);
    else if constexpr (Q == 1) return dpp_xor2(v);
    else if constexpr (Q == 3) return dpp_xor8(v);
    else return __shfl_xor(v, 1 << Q);
}

template<int Q>
__device__ __forceinline__ void lane_gate(float (&sr)[16], float (&si)[16], int lane,
                                          float ar, float ai, float br, float bi) {
    const bool hi = (lane & (1 << Q)) != 0;
    const float aiL = hi ? -ai : ai;   // bit=1 row uses conj(A), -conj(B)
    const float brL = hi ? -br : br;
    #pragma unroll
    for (int r = 0; r < 16; ++r) {
        const float pr = lane_xor<Q>(sr[r]);
        const float pi = lane_xor<Q>(si[r]);
        const float vr = sr[r], vi = si[r];
        sr[r] = ar * vr - aiL * vi + brL * pr - bi * pi;
        si[r] = ar * vi + aiL * vr + brL * pi + bi * pr;
    }
}

template<int RB>
__device__ __forceinline__ void reg_gate(float (&sr)[16], float (&si)[16],
                                         float ar, float ai, float br, float bi) {
    #pragma unroll
    for (int r = 0; r < 16; ++r) {
        if ((r & RB) == 0) {
            const int r1 = r | RB;
            const float s0r = sr[r],  s0i = si[r];
            const float s1r = sr[r1], s1i = si[r1];
            sr[r]  = ar * s0r - ai * s0i + br * s1r - bi * s1i;
            si[r]  = ar * s0i + ai * s0r + br * s1i + bi * s1r;
            sr[r1] = ar * s1r + ai * s1i - br * s0r - bi * s0i;
            si[r1] = ar * s1i - ai * s1r - br * s0i + bi * s0r;
        }
    }
}

__device__ __forceinline__ void cnot_chain(float (&sr)[16], float (&si)[16], int lane) {
    // new[j] = old[j ^ ((j&511)<<1)]
    const int srcLane = lane ^ ((lane & 31) << 1);
    float tr[16], ti[16];
    #pragma unroll
    for (int r = 0; r < 16; ++r) {
        tr[r] = __shfl(sr[r], srcLane);
        ti[r] = __shfl(si[r], srcLane);
    }
    const bool b5 = (lane & 32) != 0;   // lane bit5 feeds src reg bit0
    #pragma unroll
    for (int r = 0; r < 16; ++r) {
        const int q0 = r ^ ((r & 7) << 1);
        const int q1 = q0 ^ 1;
        sr[r] = b5 ? tr[q1] : tr[q0];
        si[r] = b5 ? ti[q1] : ti[q0];
    }
}

__global__ __launch_bounds__(256, 1) void cqv_kernel(
    const float* __restrict__ x,
    const float* __restrict__ theta,
    const float* __restrict__ alpha_raw,
    const float* __restrict__ beta_raw,
    const float* __restrict__ head_w,
    const float* __restrict__ head_b,
    const float* __restrict__ logit_scale,
    float* __restrict__ out,
    int batch)
{
    const int lane = threadIdx.x & 63;
    const int wave = threadIdx.x >> 6;
    const int s = blockIdx.x * (blockDim.x >> 6) + wave;
    if (s >= batch) return;

    // per-lane gate params: lane g in [0,30) holds gate g = layer*10 + qubit
    const int g = (lane < 30) ? lane : 0;
    const float alpha = log1pf(expf(alpha_raw[g])) + 1e-6f;
    const float beta  = tanhf(beta_raw[g]);
    const float halfE = 0.5f * PI_F * (alpha * x[s * 49 + g] + beta);
    const float cE = cosf(halfE), sE = sinf(halfE);
    const float th = 0.5f * theta[g];
    const float cT = cosf(th), sT = sinf(th);

    float sr[16], si[16];

    // ---- layer 0 on |0..0>: product state from U columns u(0)=A, u(1)=-conj(B)
    {
        float u0r[10], u0i[10], u1r[10], u1i[10];
        #pragma unroll
        for (int q = 0; q < 10; ++q) {
            const float ce = __shfl(cE, q), se = __shfl(sE, q);
            const float ct = __shfl(cT, q), st = __shfl(sT, q);
            u0r[q] = ct * ce;  u0i[q] = -st * se;   // A
            u1r[q] = ct * se;  u1i[q] = -st * ce;   // -conj(B)
        }
        float plr = 1.f, pli = 0.f;                 // product over lane bits 0..5
        #pragma unroll
        for (int q = 0; q < 6; ++q) {
            const bool bq = (lane >> q) & 1;
            const float wr = bq ? u1r[q] : u0r[q];
            const float wi = bq ? u1i[q] : u0i[q];
            const float nr = plr * wr - pli * wi;
            const float ni = plr * wi + pli * wr;
            plr = nr; pli = ni;
        }
        float t67r[4], t67i[4], t89r[4], t89i[4];   // reg bits: b0<->q6 .. b3<->q9
        #pragma unroll
        for (int a = 0; a < 4; ++a) {
            const float w6r = (a & 1) ? u1r[6] : u0r[6], w6i = (a & 1) ? u1i[6] : u0i[6];
            const float w7r = (a & 2) ? u1r[7] : u0r[7], w7i = (a & 2) ? u1i[7] : u0i[7];
            t67r[a] = w6r * w7r - w6i * w7i;  t67i[a] = w6r * w7i + w6i * w7r;
            const float w8r = (a & 1) ? u1r[8] : u0r[8], w8i = (a & 1) ? u1i[8] : u0i[8];
            const float w9r = (a & 2) ? u1r[9] : u0r[9], w9i = (a & 2) ? u1i[9] : u0i[9];
            t89r[a] = w8r * w9r - w8i * w9i;  t89i[a] = w8r * w9i + w8i * w9r;
        }
        #pragma unroll
        for (int r = 0; r < 16; ++r) {
            const float ar = t67r[r & 3] * t89r[r >> 2] - t67i[r & 3] * t89i[r >> 2];
            const float ai = t67r[r & 3] * t89i[r >> 2] + t67i[r & 3] * t89r[r >> 2];
            sr[r] = ar * plr - ai * pli;
            si[r] = ar * pli + ai * plr;
        }
    }
    cnot_chain(sr, si, lane);

    // ---- layers 1,2: rolled loop (code must stay I$-resident) ----
    #pragma unroll 1
    for (int b = 1; b < 3; ++b) {
        float arr[10], aii[10], brr[10], bii[10];
        #pragma unroll
        for (int q = 0; q < 10; ++q) {
            const int gi = b * 10 + q;
            const float ce = __shfl(cE, gi), se = __shfl(sE, gi);
            const float ct = __shfl(cT, gi), st = __shfl(sT, gi);
            arr[q] = ct * ce;  aii[q] = -st * se;
            brr[q] = -ct * se; bii[q] = -st * ce;
        }
        lane_gate<0>(sr, si, lane, arr[0], aii[0], brr[0], bii[0]);
        lane_gate<1>(sr, si, lane, arr[1], aii[1], brr[1], bii[1]);
        lane_gate<2>(sr, si, lane, arr[2], aii[2], brr[2], bii[2]);
        lane_gate<3>(sr, si, lane, arr[3], aii[3], brr[3], bii[3]);
        lane_gate<4>(sr, si, lane, arr[4], aii[4], brr[4], bii[4]);
        lane_gate<5>(sr, si, lane, arr[5], aii[5], brr[5], bii[5]);
        reg_gate<1>(sr, si, arr[6], aii[6], brr[6], bii[6]);
        reg_gate<2>(sr, si, arr[7], aii[7], brr[7], bii[7]);
        reg_gate<4>(sr, si, arr[8], aii[8], brr[8], bii[8]);
        reg_gate<8>(sr, si, arr[9], aii[9], brr[9], bii[9]);
        cnot_chain(sr, si, lane);
    }

    // ---- epilogue: <Z> head. W(i) = sum_q w_q*(1-2*bit_q(i)) ----
    float w[10];
    #pragma unroll
    for (int q = 0; q < 10; ++q) w[q] = head_w[q];
    float wlane = 0.f;
    #pragma unroll
    for (int q = 0; q < 6; ++q) wlane += ((lane >> q) & 1) ? -w[q] : w[q];
    float acc = 0.f, psum = 0.f;
    #pragma unroll
    for (int r = 0; r < 16; ++r) {
        const float p = sr[r] * sr[r] + si[r] * si[r];
        const float wr = ((r & 1) ? -w[6] : w[6]) + ((r & 2) ? -w[7] : w[7])
                       + ((r & 4) ? -w[8] : w[8]) + ((r & 8) ? -w[9] : w[9]);
        psum += p;
        acc = fmaf(wr, p, acc);
    }
    float partial = fmaf(wlane, psum, acc);
    #pragma unroll
    for (int off = 32; off >= 1; off >>= 1) partial += __shfl_xor(partial, off);

    if (lane == 0) {
        const float scale = fminf(fmaxf(logit_scale[0], 0.5f), 80.f);
        const float raw = partial + head_b[0];
        out[s] = fminf(fmaxf(scale * raw, -30.f), 30.f);
    }
}

extern "C" void kernel_launch(void* const* d_in, const int* in_sizes, int n_in,
                              void* d_out, int out_size, void* d_ws, size_t ws_size,
                              hipStream_t stream) {
    const int B = in_sizes[0] / 49;          // BATCH = 2048
    const int WPB = 4;
    dim3 block(64 * WPB);
    dim3 grid((B + WPB - 1) / WPB);
    cqv_kernel<<<grid, block, 0, stream>>>(
        (const float*)d_in[0], (const float*)d_in[1], (const float*)d_in[2],
        (const float*)d_in[3], (const float*)d_in[4], (const float*)d_in[5],
        (const float*)d_in[6], (float*)d_out, B);
}